// Round 1
// baseline (327.531 us; speedup 1.0000x reference)
//
#include <hip/hip_runtime.h>
#include <math.h>
#include <stdint.h>

#define LMAX 8
#define NPB 256   // points per block, 1 thread per point (4 waves)

// Host-computed coefficient pack, passed by value as a kernel arg.
// F[l][m] for m>=1: (-1)^m * sqrt((2l+1)/(2pi) * (l-m)!/(l+m)!)
// F[l][0]:          sqrt((2l+1)/(4pi))
// A[l][m] = (2l-1)/(l-m), B[l][m] = (l+m-1)/(l-m)
struct Coefs {
    float F[LMAX + 1][LMAX + 1];
    float A[LMAX + 1][LMAX + 1];
    float B[LMAX + 1][LMAX + 1];
};

// Per-l ping-pong staging: instead of staging all 81 columns (41.5 KB/block
// -> 3 blocks/CU = 6 waves/CU), stage one l at a time into two parity
// buffers (even l -> bufA[256*17], odd l -> bufB[256*15], 32 KiB total ->
// 5 blocks/CU, up to 20 waves/CU). Barriers are raw s_barrier with
// lgkmcnt-only waits: global stores are NEVER drained inside the loop
// (no vmcnt(0)), so the copy-out stores of all 9 l's pipeline continuously
// through the kernel and across blocks.
//
// Ping-pong safety: each thread executes s_waitcnt lgkmcnt(0) right before
// every s_barrier, so its ds_reads of buffer p (copy-out of l) are complete
// before it passes barrier l+1, which happens-before any ds_write to buffer
// p at l+2. Writes at l+1 go to the other buffer.
__global__ __launch_bounds__(NPB, 4) void solid_harmonics_kernel(
    const float* __restrict__ R, float* __restrict__ out, int N, Coefs cf)
{
    __shared__ __align__(16) float bufA[NPB * 17];  // even l (max 2l+1 = 17)
    __shared__ __align__(16) float bufB[NPB * 15];  // odd  l (max 2l+1 = 15)

    const int t = threadIdx.x;
    const int i0 = blockIdx.x * NPB;
    const int i = i0 + t;
    const int rows = min(NPB, N - i0);

    float x = 0.f, y = 0.f, z = 0.f;
    if (i < N) {
        x = R[3 * i + 0];
        y = R[3 * i + 1];
        z = R[3 * i + 2];
    }
    const float r2 = x * x + y * y + z * z;

    // c[m] + i s[m] = (x+iy)^m, built incrementally.
    float c[LMAX + 1], s[LMAX + 1];
    c[0] = 1.f; s[0] = 0.f;

    // Rolling Q rows: Qcur = row l, Qm1 = row l-1, Qm2 = row l-2.
    float Qcur[LMAX + 1], Qm1[LMAX + 1], Qm2[LMAX + 1];
    Qcur[0] = 1.f;

#pragma unroll
    for (int l = 0; l <= LMAX; ++l) {
        if (l >= 1) {
#pragma unroll
            for (int m = 0; m < l - 1; ++m) Qm2[m] = Qm1[m];
#pragma unroll
            for (int m = 0; m < l; ++m) Qm1[m] = Qcur[m];
            c[l] = x * c[l - 1] - y * s[l - 1];
            s[l] = x * s[l - 1] + y * c[l - 1];
            Qcur[l]     = -(2.f * l - 1.f) * Qm1[l - 1];
            Qcur[l - 1] =  (2.f * l - 1.f) * z * Qm1[l - 1];
#pragma unroll
            for (int m = l - 2; m >= 0; --m)
                Qcur[m] = cf.A[l][m] * z * Qm1[m] - cf.B[l][m] * r2 * Qm2[m];
        }

        const int stride = 2 * l + 1;
        float* buf = (l & 1) ? bufB : bufA;
        // Odd row stride -> <=2-way bank alias on the scalar ds_writes (free).
        float* row = &buf[t * stride];
        row[l] = cf.F[l][0] * Qcur[0];
#pragma unroll
        for (int m = 1; m <= l; ++m) {
            const float fq = cf.F[l][m] * Qcur[m];
            row[l - m] = fq * s[m];
            row[l + m] = fq * c[m];
        }

        // All lanes' rows for this l staged. lgkm-only wait + raw barrier:
        // outstanding global stores (previous l's copy-out) stay in flight.
        asm volatile("s_waitcnt lgkmcnt(0)" ::: "memory");
        __builtin_amdgcn_sched_barrier(0);
        __builtin_amdgcn_s_barrier();
        __builtin_amdgcn_sched_barrier(0);

        // Cooperative coalesced copy-out of this block's span for l.
        // Full blocks: E = 256*(2l+1) divisible by 4; tail (rows=64 at
        // N=1e6) also divisible. obase is 16B-aligned since i0 % 256 == 0.
        float* obase = out + (size_t)N * (size_t)(l * l) + (size_t)i0 * (size_t)stride;
        const int E = rows * stride;
        if (((E & 3) == 0) && ((((uintptr_t)obase) & 15u) == 0)) {
            const int E4 = E >> 2;
            const float4* s4 = (const float4*)buf;
            float4* o4 = (float4*)obase;
            for (int e = t; e < E4; e += NPB) o4[e] = s4[e];
        } else {
            for (int e = t; e < E; e += NPB) obase[e] = buf[e];
        }
        // No trailing barrier: the next iteration writes the OTHER buffer,
        // and its pre-barrier lgkmcnt(0) ordering protects this one.
    }
}

extern "C" void kernel_launch(void* const* d_in, const int* in_sizes, int n_in,
                              void* d_out, int out_size, void* d_ws, size_t ws_size,
                              hipStream_t stream) {
    const float* R = (const float*)d_in[0];
    float* out = (float*)d_out;
    const int N = in_sizes[0] / 3;

    Coefs cf;
    double fact[2 * LMAX + 1];
    fact[0] = 1.0;
    for (int k = 1; k <= 2 * LMAX; ++k) fact[k] = fact[k - 1] * (double)k;
    const double PI = 3.14159265358979323846;
    for (int l = 0; l <= LMAX; ++l) {
        for (int m = 0; m <= LMAX; ++m) { cf.F[l][m] = 0.f; cf.A[l][m] = 0.f; cf.B[l][m] = 0.f; }
        cf.F[l][0] = (float)sqrt((2.0 * l + 1.0) / (4.0 * PI));
        for (int m = 1; m <= l; ++m) {
            double sign = (m & 1) ? -1.0 : 1.0;
            cf.F[l][m] = (float)(sign * sqrt((2.0 * l + 1.0) / (2.0 * PI)
                                             * fact[l - m] / fact[l + m]));
        }
        for (int m = 0; m <= l - 2; ++m) {
            cf.A[l][m] = (float)((2.0 * l - 1.0) / (double)(l - m));
            cf.B[l][m] = (float)((double)(l + m - 1) / (double)(l - m));
        }
    }

    const int grid = (N + NPB - 1) / NPB;
    solid_harmonics_kernel<<<grid, NPB, 0, stream>>>(R, out, N, cf);
}